// Round 1
// 395.048 us; speedup vs baseline: 1.0307x; 1.0307x over previous
//
#include <hip/hip_runtime.h>
#include <math.h>

#define B 8
#define C 512
#define K 19
#define HW 16384
#define ROWS (B * K)             // 152
#define L2E 1.44269504088896340736f

// gather config
#define NW 4                     // waves per block
#define CPW 4                    // c-rows per wave -> acc[4][19] = 76 VGPRs
#define CPB (CPW * NW)           // 16 c-rows per block
#define CG (C / CPB)             // 32 c-groups
#define NSC 4                    // grid = 8*32*4 = 1024 = 4 blocks/CU
#define SCHUNK (HW / NSC)        // 4096 s per block
#define TS 256                   // s-tile staged in LDS
#define NT (SCHUNK / TS)         // 16 tiles per block

typedef __attribute__((address_space(3))) unsigned int lds_u32;
typedef const __attribute__((address_space(1))) unsigned int glb_u32;

// Pass 1: full softmax per (b,k) row -> probs[] in workspace (10 MB).
// One block per row, 1024 threads; each thread owns 16 elements held in
// registers (single read of aux, single exp2 pass, single write of probs).
__global__ __launch_bounds__(1024)
void probs_kernel(const float* __restrict__ aux, float* __restrict__ probs) {
    int row  = blockIdx.x;                 // 0..151
    int tid  = threadIdx.x;                // 0..1023
    int lane = tid & 63;
    int wave = tid >> 6;
    __shared__ float red[16];

    const float4* x4 = (const float4*)(aux + (size_t)row * HW);
    float4*       p4 = (float4*)(probs + (size_t)row * HW);

    float4 v[4];
    #pragma unroll
    for (int i = 0; i < 4; i++) v[i] = x4[tid + i * 1024];

    float m = -INFINITY;
    #pragma unroll
    for (int i = 0; i < 4; i++)
        m = fmaxf(m, fmaxf(fmaxf(v[i].x, v[i].y), fmaxf(v[i].z, v[i].w)));
    #pragma unroll
    for (int off = 32; off > 0; off >>= 1) m = fmaxf(m, __shfl_xor(m, off, 64));
    if (lane == 0) red[wave] = m;
    __syncthreads();
    #pragma unroll
    for (int w = 0; w < 16; w++) m = fmaxf(m, red[w]);
    __syncthreads();                       // red[] reads done before reuse

    float nm = -m * L2E;
    float s = 0.f;
    #pragma unroll
    for (int i = 0; i < 4; i++) {
        v[i].x = exp2f(fmaf(v[i].x, L2E, nm));
        v[i].y = exp2f(fmaf(v[i].y, L2E, nm));
        v[i].z = exp2f(fmaf(v[i].z, L2E, nm));
        v[i].w = exp2f(fmaf(v[i].w, L2E, nm));
        s += (v[i].x + v[i].y) + (v[i].z + v[i].w);
    }
    #pragma unroll
    for (int off = 32; off > 0; off >>= 1) s += __shfl_xor(s, off, 64);
    if (lane == 0) red[wave] = s;
    __syncthreads();
    float Z = 0.f;
    #pragma unroll
    for (int w = 0; w < 16; w++) Z += red[w];
    float inv = 1.0f / Z;

    #pragma unroll
    for (int i = 0; i < 4; i++) {
        float4 o;
        o.x = v[i].x * inv; o.y = v[i].y * inv;
        o.z = v[i].z * inv; o.w = v[i].w * inv;
        p4[tid + i * 1024] = o;
    }
}

// Gather. ALLOCATOR LAW (R1-R5 measured): VGPR budget = 512/(2*declared_min_waves_per_eu).
// waves_per_eu(2) -> budget 128. Declaring 4 -> 64 VGPRs -> catastrophic spill.
// Do NOT "fix" this to match actual occupancy. Occupancy comes from LDS:
// 38,912 B -> 4 blocks/CU = 16 waves/CU.
//
// vs previous version: probs are precomputed, so staging is pure async copy
// (global_load_lds dwordx4: wave-uniform LDS base + lane*16B, linear dest,
// ~5 issues/wave/tile) instead of 19 scalar loads + exp2 + LDS writes per
// thread. Also drops the 38 stats registers. XCD swizzle co-locates the 32
// cg-blocks sharing one (b,sc) probs chunk (304 KB) on one XCD's L2.
__global__ __launch_bounds__(256)
__attribute__((amdgpu_waves_per_eu(2)))
void gather_kernel(const float* __restrict__ feats, const float* __restrict__ probs,
                   float* __restrict__ out) {
    __shared__ float plds[2][K][TS];       // 38,912 B -> 4 blocks/CU

    int bid = blockIdx.x;                  // 0..1023
    // consecutive bids round-robin XCDs; give each XCD 4 whole (b,sc) groups
    int xcd = bid & 7;
    int lid = xcd * 128 + (bid >> 3);
    int cg  = lid & (CG - 1);
    int grp = lid >> 5;                    // b*NSC + sc
    int sc  = grp & (NSC - 1);
    int b   = grp >> 2;

    int tid  = threadIdx.x;
    int lane = tid & 63;
    int wave = tid >> 6;
    int c0   = cg * CPB + wave * CPW;

    const float* Pbase = probs + (size_t)b * K * HW + sc * SCHUNK;
    const float* Fbase = feats + ((size_t)b * C + c0) * HW + sc * SCHUNK;

    float acc[CPW][K];
    #pragma unroll
    for (int c = 0; c < CPW; c++)
        #pragma unroll
        for (int k = 0; k < K; k++) acc[c][k] = 0.f;

    // prologue: async-stage probs tile 0 + load feats tile 0
    for (int k = wave; k < K; k += NW)
        __builtin_amdgcn_global_load_lds((glb_u32*)(Pbase + (size_t)k * HW + lane * 4),
                                         (lds_u32*)&plds[0][k][0], 16, 0, 0);
    float4 f_cur[CPW], f_next[CPW];
    #pragma unroll
    for (int c = 0; c < CPW; c++)
        f_cur[c] = *(const float4*)(Fbase + c * HW + lane * 4);

    for (int t = 0; t < NT; t++) {
        int buf = t & 1;
        __syncthreads();   // drains vmcnt: plds[buf] staged; prior readers of buf^1 done

        if (t + 1 < NT) {
            int s1 = (t + 1) * TS;
            #pragma unroll
            for (int c = 0; c < CPW; c++)
                f_next[c] = *(const float4*)(Fbase + c * HW + s1 + lane * 4);
            for (int k = wave; k < K; k += NW)
                __builtin_amdgcn_global_load_lds((glb_u32*)(Pbase + (size_t)k * HW + s1 + lane * 4),
                                                 (lds_u32*)&plds[buf ^ 1][k][0], 16, 0, 0);
        }

        // FMA phase on tile t: f_cur (regs) x plds[buf] (ds_read_b128)
        #pragma unroll
        for (int k = 0; k < K; k++) {
            float4 pv = *(const float4*)(&plds[buf][k][lane * 4]);
            #pragma unroll
            for (int c = 0; c < CPW; c++) {
                acc[c][k] = fmaf(pv.x, f_cur[c].x, acc[c][k]);
                acc[c][k] = fmaf(pv.y, f_cur[c].y, acc[c][k]);
                acc[c][k] = fmaf(pv.z, f_cur[c].z, acc[c][k]);
                acc[c][k] = fmaf(pv.w, f_cur[c].w, acc[c][k]);
            }
        }
        #pragma unroll
        for (int c = 0; c < CPW; c++) f_cur[c] = f_next[c];
    }

    // butterfly reduce over 64 lanes, then one atomic per (c,k) per block
    #pragma unroll
    for (int c = 0; c < CPW; c++)
        #pragma unroll
        for (int k = 0; k < K; k++) {
            float v = acc[c][k];
            #pragma unroll
            for (int off = 32; off > 0; off >>= 1) v += __shfl_xor(v, off, 64);
            if (lane == 0)
                atomicAdd(&out[((size_t)b * C + c0 + c) * K + k], v);
        }
}

extern "C" void kernel_launch(void* const* d_in, const int* in_sizes, int n_in,
                              void* d_out, int out_size, void* d_ws, size_t ws_size,
                              hipStream_t stream) {
    const float* feats = (const float*)d_in[0];   // bb_feats [8,512,128,128]
    const float* aux   = (const float*)d_in[1];   // aux_out  [8,19,128,128]
    float* out   = (float*)d_out;                 // [8,512,19,1]
    float* probs = (float*)d_ws;                  // [8,19,16384] = 10 MB

    hipMemsetAsync(d_out, 0, (size_t)out_size * sizeof(float), stream);
    probs_kernel<<<ROWS, 1024, 0, stream>>>(aux, probs);
    gather_kernel<<<B * CG * NSC, 256, 0, stream>>>(feats, probs, out);
}